// Round 3
// baseline (2755.704 us; speedup 1.0000x reference)
//
#include <hip/hip_runtime.h>
#include <hip/hip_bf16.h>
#include <stdint.h>

#define M_DIM 8192
#define N_DIM 4096
#define K_DIM 4096
#define NNZ   1600000

typedef __attribute__((ext_vector_type(8))) short bf16x8;
typedef __attribute__((ext_vector_type(4))) float f32x4;

// workspace layout (bytes)
static const size_t WF32_OFF  = 0;
static const size_t WBF16_OFF = 64ull << 20;
static const size_t XB_OFF    = 96ull << 20;
static const size_t WS_NEED   = 160ull << 20;

__device__ __forceinline__ unsigned short f2bf(float f) {
    union { float f; uint32_t u; } a; a.f = f;
    uint32_t u = a.u;
    uint32_t r = (u + 0x7FFFu + ((u >> 16) & 1u)) >> 16;   // RNE
    return (unsigned short)r;
}

__global__ void scatter_kernel(const int* __restrict__ idx,
                               const float* __restrict__ vals,
                               float* __restrict__ W) {
    int t = blockIdx.x * blockDim.x + threadIdx.x;
    if (t < NNZ) {
        int2 rc = ((const int2*)idx)[t];
        atomicAdd(&W[(size_t)rc.x * K_DIM + rc.y], vals[t]);
    }
}

__global__ void f32_to_bf16_kernel(const float* __restrict__ src,
                                   unsigned short* __restrict__ dst, int n4) {
    int t = blockIdx.x * blockDim.x + threadIdx.x;
    if (t < n4) {
        float4 v = ((const float4*)src)[t];
        ushort4 o;
        o.x = f2bf(v.x); o.y = f2bf(v.y); o.z = f2bf(v.z); o.w = f2bf(v.w);
        ((ushort4*)dst)[t] = o;
    }
}

// ---------------------------------------------------------------------------
// 256x256 bf16 MFMA GEMM, BK=32, 64KB LDS -> 2 blocks/CU (cross-block overlap).
// 8 waves (2M x 4N), per-wave 128x64 out. 2 barriers / K-tile, counted vmcnt.
// Swizzle: 16B slot u at row r stored at u ^ ((r>>1)&3)  (2-way = free);
// inverse-swizzled global source keeps gload_lds dest linear (rule 21).
// ---------------------------------------------------------------------------
#define GLOAD16(gp, lp) __builtin_amdgcn_global_load_lds( \
    (const __attribute__((address_space(1))) void*)(gp),  \
    (__attribute__((address_space(3))) void*)(lp), 16, 0, 0)
#define VMCNT(n)   asm volatile("s_waitcnt vmcnt(" #n ")" ::: "memory")
#define LGKMCNT(n) asm volatile("s_waitcnt lgkmcnt(" #n ")" ::: "memory")
#define BAR()    __builtin_amdgcn_s_barrier()
#define SCHED0() __builtin_amdgcn_sched_barrier(0)

// frag read from 256x32 swizzled tile
#define FRAG(T, r) \
    (*(const bf16x8*)&(T)[(r) * 32 + ((l4 ^ (((r) >> 1) & 3)) << 3)])

// stage one 256x32 tile of A and B (4 gload_lds x 512 threads x 16B)
#define STAGE_T(buf, t) do {                                              \
    const size_t kb = (size_t)(t) * 32;                                   \
    GLOAD16(Ab + (size_t)ra0 * K_DIM + kb + ca0, &sA[buf][wid * 512]);    \
    GLOAD16(Ab + (size_t)ra1 * K_DIM + kb + ca1, &sA[buf][4096 + wid * 512]); \
    GLOAD16(Bb + (size_t)ra0 * K_DIM + kb + ca0, &sB[buf][wid * 512]);    \
    GLOAD16(Bb + (size_t)ra1 * K_DIM + kb + ca1, &sB[buf][4096 + wid * 512]); \
  } while (0)

__global__ __launch_bounds__(512, 4) void gemm256_bk32(
        const __hip_bfloat16* __restrict__ A,   // M x K
        const __hip_bfloat16* __restrict__ B,   // N x K
        float* __restrict__ C)                  // M x N
{
    __shared__ __align__(16) __hip_bfloat16 sA[2][256 * 32];
    __shared__ __align__(16) __hip_bfloat16 sB[2][256 * 32];

    const int tid  = threadIdx.x;
    const int lane = tid & 63;
    const int wid  = tid >> 6;
    const int wr   = wid >> 2;      // 0..1  (128-row half)
    const int wc   = wid & 3;       // 0..3  (64-col slice)
    const int l15  = lane & 15, l4 = lane >> 4;

    // XCD-aware bijective swizzle (nwg = 512, %8 == 0)
    const int bid = blockIdx.x;
    const int swz = (bid & 7) * 64 + (bid >> 3);
    const int m0  = (swz >> 4) * 256;   // 32 m-tiles
    const int n0  = (swz & 15) * 256;   // 16 n-tiles

    // staging geometry: slot s = i*512 + tid; r = s>>2, u = s&3
    const int r0v = tid >> 2,        u0 = tid & 3;
    const int ra0 = r0v,             ca0 = ((u0 ^ ((r0v >> 1) & 3)) << 3);
    const int r1v = 128 + (tid >> 2);
    const int ra1 = r1v,             ca1 = ((u0 ^ ((r1v >> 1) & 3)) << 3);

    const __hip_bfloat16* Ab = A + (size_t)m0 * K_DIM;
    const __hip_bfloat16* Bb = B + (size_t)n0 * K_DIM;

    f32x4 acc[8][4] = {};

    // prologue: tiles 0 and 1
    STAGE_T(0, 0);
    STAGE_T(1, 1);
    VMCNT(4);          // tile 0 landed; tile 1 in flight
    BAR();
    SCHED0();

    const int NT = K_DIM / 32;      // 128
    for (int t = 0; t < NT; ++t) {
        const int c = t & 1;
        const __hip_bfloat16* TA = sA[c];
        const __hip_bfloat16* TB = sB[c];

        bf16x8 bf[4], af[8];
        #pragma unroll
        for (int n = 0; n < 4; ++n) bf[n] = FRAG(TB, wc * 64 + n * 16 + l15);
        #pragma unroll
        for (int m = 0; m < 4; ++m) af[m] = FRAG(TA, wr * 128 + m * 16 + l15);
        SCHED0();                                   // pin issue order of read groups
        #pragma unroll
        for (int m = 4; m < 8; ++m) af[m] = FRAG(TA, wr * 128 + m * 16 + l15);

        __builtin_amdgcn_s_setprio(1);
        LGKMCNT(4); SCHED0();                       // first 8 reads (bf + af[0..3]) done
        #pragma unroll
        for (int m = 0; m < 4; ++m)
            #pragma unroll
            for (int n = 0; n < 4; ++n)
                acc[m][n] = __builtin_amdgcn_mfma_f32_16x16x32_bf16(
                                af[m], bf[n], acc[m][n], 0, 0, 0);
        LGKMCNT(0); SCHED0();
        #pragma unroll
        for (int m = 4; m < 8; ++m)
            #pragma unroll
            for (int n = 0; n < 4; ++n)
                acc[m][n] = __builtin_amdgcn_mfma_f32_16x16x32_bf16(
                                af[m], bf[n], acc[m][n], 0, 0, 0);
        __builtin_amdgcn_s_setprio(0);

        BAR();                  // all waves done reading buf c
        SCHED0();
        if (t + 2 < NT) {
            STAGE_T(c, t + 2);  // overwrite buf c with tile t+2
            VMCNT(4);           // drains tile t+1 (issued last iter); t+2 in flight
        } else {
            VMCNT(0);           // tail: drain remaining loads
        }
        BAR();                  // entry barrier of tile t+1: buf c^1 valid for all
        SCHED0();
    }

    // epilogue: ReLU + fp32 store
    const int row_base = m0 + wr * 128;
    const int col_base = n0 + wc * 64;
    #pragma unroll
    for (int m = 0; m < 8; ++m)
        #pragma unroll
        for (int n = 0; n < 4; ++n) {
            const f32x4 v = acc[m][n];
            const int col = col_base + n * 16 + l15;
            #pragma unroll
            for (int j = 0; j < 4; ++j) {
                const int row = row_base + m * 16 + l4 * 4 + j;
                C[(size_t)row * N_DIM + col] = fmaxf(v[j], 0.0f);
            }
        }
}

// ---------------------------------------------------------------------------
// fp32 fallback GEMM (only if ws_size < 160MB)
// ---------------------------------------------------------------------------
__global__ void gemm_f32_fallback(const float* __restrict__ A,
                                  const float* __restrict__ W,
                                  float* __restrict__ C) {
    __shared__ float As[64][17];
    __shared__ float Bs[64][17];
    const int tx = threadIdx.x & 15, ty = threadIdx.x >> 4;
    const int m0 = blockIdx.y * 64, n0 = blockIdx.x * 64;
    float acc[4][4] = {};
    for (int kt = 0; kt < K_DIM; kt += 16) {
        #pragma unroll
        for (int i = 0; i < 4; ++i) {
            int e = threadIdx.x + i * 256;
            int r = e >> 4, k = e & 15;
            As[r][k] = A[(size_t)(m0 + r) * K_DIM + kt + k];
            Bs[r][k] = W[(size_t)(n0 + r) * K_DIM + kt + k];
        }
        __syncthreads();
        #pragma unroll
        for (int k = 0; k < 16; ++k) {
            float av[4], bv[4];
            #pragma unroll
            for (int i = 0; i < 4; ++i) av[i] = As[ty * 4 + i][k];
            #pragma unroll
            for (int i = 0; i < 4; ++i) bv[i] = Bs[tx * 4 + i][k];
            #pragma unroll
            for (int i = 0; i < 4; ++i)
                #pragma unroll
                for (int j = 0; j < 4; ++j) acc[i][j] += av[i] * bv[j];
        }
        __syncthreads();
    }
    #pragma unroll
    for (int i = 0; i < 4; ++i)
        #pragma unroll
        for (int j = 0; j < 4; ++j)
            C[(size_t)(m0 + ty * 4 + i) * N_DIM + n0 + tx * 4 + j] =
                fmaxf(acc[i][j], 0.0f);
}

extern "C" void kernel_launch(void* const* d_in, const int* in_sizes, int n_in,
                              void* d_out, int out_size, void* d_ws, size_t ws_size,
                              hipStream_t stream) {
    const float* x       = (const float*)d_in[0];
    const int*   indices = (const int*)d_in[1];
    const float* values  = (const float*)d_in[2];
    float*       out     = (float*)d_out;

    float* Wf = (float*)((char*)d_ws + WF32_OFF);

    // 1. zero + scatter-build W (fp32, duplicates accumulate)
    hipMemsetAsync(Wf, 0, (size_t)N_DIM * K_DIM * sizeof(float), stream);
    scatter_kernel<<<(NNZ + 255) / 256, 256, 0, stream>>>(indices, values, Wf);

    if (ws_size >= WS_NEED) {
        unsigned short* Wb = (unsigned short*)((char*)d_ws + WBF16_OFF);
        unsigned short* xb = (unsigned short*)((char*)d_ws + XB_OFF);

        // 2. fp32 -> bf16 conversions
        {
            int n4 = (N_DIM * K_DIM) / 4;
            f32_to_bf16_kernel<<<(n4 + 255) / 256, 256, 0, stream>>>(Wf, Wb, n4);
        }
        {
            int n4 = (M_DIM * K_DIM) / 4;
            f32_to_bf16_kernel<<<(n4 + 255) / 256, 256, 0, stream>>>(x, xb, n4);
        }

        // 3. 256^2 BK=32 bf16 MFMA GEMM + ReLU (2 blocks/CU)
        gemm256_bk32<<<(M_DIM / 256) * (N_DIM / 256), 512, 0, stream>>>(
            (const __hip_bfloat16*)xb, (const __hip_bfloat16*)Wb, out);
    } else {
        gemm_f32_fallback<<<dim3(N_DIM / 64, M_DIM / 64), 256, 0, stream>>>(
            x, Wf, out);
    }
}

// Round 4
// 467.429 us; speedup vs baseline: 5.8954x; 5.8954x over previous
//
#include <hip/hip_runtime.h>
#include <hip/hip_bf16.h>
#include <stdint.h>

#define M_DIM 8192
#define N_DIM 4096
#define K_DIM 4096
#define NNZ   1600000

typedef __attribute__((ext_vector_type(8))) short bf16x8;
typedef __attribute__((ext_vector_type(4))) float f32x4;

// workspace layout (bytes)
static const size_t WF32_OFF  = 0;
static const size_t WBF16_OFF = 64ull << 20;
static const size_t XB_OFF    = 96ull << 20;
static const size_t WS_NEED   = 160ull << 20;

__device__ __forceinline__ unsigned short f2bf(float f) {
    union { float f; uint32_t u; } a; a.f = f;
    uint32_t u = a.u;
    uint32_t r = (u + 0x7FFFu + ((u >> 16) & 1u)) >> 16;   // RNE
    return (unsigned short)r;
}

__global__ void scatter_kernel(const int* __restrict__ idx,
                               const float* __restrict__ vals,
                               float* __restrict__ W) {
    int t = blockIdx.x * blockDim.x + threadIdx.x;
    if (t < NNZ) {
        int2 rc = ((const int2*)idx)[t];
        atomicAdd(&W[(size_t)rc.x * K_DIM + rc.y], vals[t]);
    }
}

__global__ void f32_to_bf16_kernel(const float* __restrict__ src,
                                   unsigned short* __restrict__ dst, int n4) {
    int t = blockIdx.x * blockDim.x + threadIdx.x;
    if (t < n4) {
        float4 v = ((const float4*)src)[t];
        ushort4 o;
        o.x = f2bf(v.x); o.y = f2bf(v.y); o.z = f2bf(v.z); o.w = f2bf(v.w);
        ((ushort4*)dst)[t] = o;
    }
}

// ---------------------------------------------------------------------------
// 256x256 bf16 MFMA GEMM, BK=64, 8 waves (2Mx4N), per-wave 128x64 out.
// TWO raw barriers per K-tile; counted vmcnt(4) (never 0 in steady state);
// compiler-scheduled lgkmcnt (no manual pins inside segments).
//   seg1: read aLo + all b (16 ds_read_b128), stage A(t+1)->c^1, 16 MFMA
//   BAR1  (fences all B-reads of buf c)
//   seg2: read aHi (8), stage B(t+2)->c (B region free), 16 MFMA
//   vmcnt(4) -> drains A(t+1),B(t+1); keeps B(t+2) in flight; BAR2
// Swizzle (verified 0-conflict in r1/r2): 16B slot u at row r stored at
// u^(r&7); inverse-swizzled global source keeps gload_lds dest linear.
// ---------------------------------------------------------------------------
#define GLOAD16(gp, lp) __builtin_amdgcn_global_load_lds( \
    (const __attribute__((address_space(1))) void*)(gp),  \
    (__attribute__((address_space(3))) void*)(lp), 16, 0, 0)
#define VMCNT(n)   asm volatile("s_waitcnt vmcnt(" #n ")" ::: "memory")
#define BAR()    __builtin_amdgcn_s_barrier()
#define SCHED0() __builtin_amdgcn_sched_barrier(0)

// frag read from 256x64 swizzled tile: row r, k-slot kk in {0,1}
#define FRAG(T, r, kk) \
    (*(const bf16x8*)&(T)[(r) * 64 + (((((kk) << 2) + l4) ^ ((r) & 7)) << 3)])

// stage one full 256x64 tile (4 gload_lds x 512 threads x 16B)
#define STAGE_A(buf, tt) do {                                                 \
    const size_t kb = (size_t)(tt) * 64;                                      \
    GLOAD16(Ab + (size_t)(0 * 64 + rbase) * K_DIM + kb + cs, &sA[buf][0 * 4096 + wid * 512]); \
    GLOAD16(Ab + (size_t)(1 * 64 + rbase) * K_DIM + kb + cs, &sA[buf][1 * 4096 + wid * 512]); \
    GLOAD16(Ab + (size_t)(2 * 64 + rbase) * K_DIM + kb + cs, &sA[buf][2 * 4096 + wid * 512]); \
    GLOAD16(Ab + (size_t)(3 * 64 + rbase) * K_DIM + kb + cs, &sA[buf][3 * 4096 + wid * 512]); \
  } while (0)
#define STAGE_B(buf, tt) do {                                                 \
    const size_t kb = (size_t)(tt) * 64;                                      \
    GLOAD16(Bb + (size_t)(0 * 64 + rbase) * K_DIM + kb + cs, &sB[buf][0 * 4096 + wid * 512]); \
    GLOAD16(Bb + (size_t)(1 * 64 + rbase) * K_DIM + kb + cs, &sB[buf][1 * 4096 + wid * 512]); \
    GLOAD16(Bb + (size_t)(2 * 64 + rbase) * K_DIM + kb + cs, &sB[buf][2 * 4096 + wid * 512]); \
    GLOAD16(Bb + (size_t)(3 * 64 + rbase) * K_DIM + kb + cs, &sB[buf][3 * 4096 + wid * 512]); \
  } while (0)

__global__ __launch_bounds__(512, 2) void gemm256_v4(
        const __hip_bfloat16* __restrict__ A,   // M x K
        const __hip_bfloat16* __restrict__ B,   // N x K
        float* __restrict__ C)                  // M x N
{
    __shared__ __align__(16) __hip_bfloat16 sA[2][256 * 64];
    __shared__ __align__(16) __hip_bfloat16 sB[2][256 * 64];

    const int tid  = threadIdx.x;
    const int lane = tid & 63;
    const int wid  = tid >> 6;
    const int wr   = wid >> 2;      // 0..1  (128-row half)
    const int wc   = wid & 3;       // 0..3  (64-col slice)
    const int l15  = lane & 15, l4 = lane >> 4;

    // XCD-aware bijective swizzle (nwg = 512, %8 == 0)
    const int bid = blockIdx.x;
    const int swz = (bid & 7) * 64 + (bid >> 3);
    const int m0  = (swz >> 4) * 256;   // 32 m-tiles
    const int n0  = (swz & 15) * 256;   // 16 n-tiles

    // staging geometry: gload i covers rows i*64 + (tid>>3); 16B col-slot
    // u = tid&7, inverse-swizzled source col = (u ^ (row&7))*8 (row&7 indep of i)
    const int rbase = tid >> 3;
    const int cs    = ((tid & 7) ^ (rbase & 7)) << 3;

    const __hip_bfloat16* Ab = A + (size_t)m0 * K_DIM;
    const __hip_bfloat16* Bb = B + (size_t)n0 * K_DIM;

    f32x4 acc[8][4] = {};

    // prologue: A(0),B(0) -> buf0 ; B(1) -> buf1 ; A(1) staged inside t=0
    STAGE_A(0, 0);
    STAGE_B(0, 0);
    STAGE_B(1, 1);
    VMCNT(4);          // A(0),B(0) landed; B(1) in flight
    BAR();
    SCHED0();

    const int NT = K_DIM / 64;      // 64
    for (int t = 0; t < NT; ++t) {
        const int c = t & 1;
        const __hip_bfloat16* TA = sA[c];
        const __hip_bfloat16* TB = sB[c];

        // ================= segment 1: mLo x (all n) =================
        if (t + 1 < NT) STAGE_A(c ^ 1, t + 1);      // A(t+1) -> other buf

        bf16x8 b0[4], a0[4];
        #pragma unroll
        for (int n = 0; n < 4; ++n) b0[n] = FRAG(TB, wc * 64 + n * 16 + l15, 0);
        #pragma unroll
        for (int m = 0; m < 4; ++m) a0[m] = FRAG(TA, wr * 128 + m * 16 + l15, 0);
        __builtin_amdgcn_s_setprio(1);
        #pragma unroll
        for (int m = 0; m < 4; ++m)
            #pragma unroll
            for (int n = 0; n < 4; ++n)
                acc[m][n] = __builtin_amdgcn_mfma_f32_16x16x32_bf16(
                                a0[m], b0[n], acc[m][n], 0, 0, 0);
        __builtin_amdgcn_s_setprio(0);

        bf16x8 b1[4], a1[4];
        #pragma unroll
        for (int n = 0; n < 4; ++n) b1[n] = FRAG(TB, wc * 64 + n * 16 + l15, 1);
        #pragma unroll
        for (int m = 0; m < 4; ++m) a1[m] = FRAG(TA, wr * 128 + m * 16 + l15, 1);
        __builtin_amdgcn_s_setprio(1);
        #pragma unroll
        for (int m = 0; m < 4; ++m)
            #pragma unroll
            for (int n = 0; n < 4; ++n)
                acc[m][n] = __builtin_amdgcn_mfma_f32_16x16x32_bf16(
                                a1[m], b1[n], acc[m][n], 0, 0, 0);
        __builtin_amdgcn_s_setprio(0);

        BAR();              // all B-reads (and aLo) of buf c complete
        SCHED0();

        // ================= segment 2: mHi x (all n) =================
        if (t + 2 < NT) STAGE_B(c, t + 2);          // B region of c is free

        bf16x8 h0[4], h1[4];
        #pragma unroll
        for (int m = 0; m < 4; ++m) h0[m] = FRAG(TA, wr * 128 + 64 + m * 16 + l15, 0);
        #pragma unroll
        for (int m = 0; m < 4; ++m) h1[m] = FRAG(TA, wr * 128 + 64 + m * 16 + l15, 1);
        __builtin_amdgcn_s_setprio(1);
        #pragma unroll
        for (int m = 0; m < 4; ++m)
            #pragma unroll
            for (int n = 0; n < 4; ++n)
                acc[4 + m][n] = __builtin_amdgcn_mfma_f32_16x16x32_bf16(
                                h0[m], b0[n], acc[4 + m][n], 0, 0, 0);
        #pragma unroll
        for (int m = 0; m < 4; ++m)
            #pragma unroll
            for (int n = 0; n < 4; ++n)
                acc[4 + m][n] = __builtin_amdgcn_mfma_f32_16x16x32_bf16(
                                h1[m], b1[n], acc[4 + m][n], 0, 0, 0);
        __builtin_amdgcn_s_setprio(0);

        // ---- tile boundary: counted drain, raw barrier ----
        if (t < NT - 2) { VMCNT(4); } else { VMCNT(0); }
        BAR();
        SCHED0();
    }

    // epilogue: ReLU + fp32 store
    const int row_base = m0 + wr * 128;
    const int col_base = n0 + wc * 64;
    #pragma unroll
    for (int m = 0; m < 8; ++m)
        #pragma unroll
        for (int n = 0; n < 4; ++n) {
            const f32x4 v = acc[m][n];
            const int col = col_base + n * 16 + l15;
            #pragma unroll
            for (int j = 0; j < 4; ++j) {
                const int row = row_base + m * 16 + l4 * 4 + j;
                C[(size_t)row * N_DIM + col] = fmaxf(v[j], 0.0f);
            }
        }
}

// ---------------------------------------------------------------------------
// fp32 fallback GEMM (only if ws_size < 160MB)
// ---------------------------------------------------------------------------
__global__ void gemm_f32_fallback(const float* __restrict__ A,
                                  const float* __restrict__ W,
                                  float* __restrict__ C) {
    __shared__ float As[64][17];
    __shared__ float Bs[64][17];
    const int tx = threadIdx.x & 15, ty = threadIdx.x >> 4;
    const int m0 = blockIdx.y * 64, n0 = blockIdx.x * 64;
    float acc[4][4] = {};
    for (int kt = 0; kt < K_DIM; kt += 16) {
        #pragma unroll
        for (int i = 0; i < 4; ++i) {
            int e = threadIdx.x + i * 256;
            int r = e >> 4, k = e & 15;
            As[r][k] = A[(size_t)(m0 + r) * K_DIM + kt + k];
            Bs[r][k] = W[(size_t)(n0 + r) * K_DIM + kt + k];
        }
        __syncthreads();
        #pragma unroll
        for (int k = 0; k < 16; ++k) {
            float av[4], bv[4];
            #pragma unroll
            for (int i = 0; i < 4; ++i) av[i] = As[ty * 4 + i][k];
            #pragma unroll
            for (int i = 0; i < 4; ++i) bv[i] = Bs[tx * 4 + i][k];
            #pragma unroll
            for (int i = 0; i < 4; ++i)
                #pragma unroll
                for (int j = 0; j < 4; ++j) acc[i][j] += av[i] * bv[j];
        }
        __syncthreads();
    }
    #pragma unroll
    for (int i = 0; i < 4; ++i)
        #pragma unroll
        for (int j = 0; j < 4; ++j)
            C[(size_t)(m0 + ty * 4 + i) * N_DIM + n0 + tx * 4 + j] =
                fmaxf(acc[i][j], 0.0f);
}

extern "C" void kernel_launch(void* const* d_in, const int* in_sizes, int n_in,
                              void* d_out, int out_size, void* d_ws, size_t ws_size,
                              hipStream_t stream) {
    const float* x       = (const float*)d_in[0];
    const int*   indices = (const int*)d_in[1];
    const float* values  = (const float*)d_in[2];
    float*       out     = (float*)d_out;

    float* Wf = (float*)((char*)d_ws + WF32_OFF);

    // 1. zero + scatter-build W (fp32, duplicates accumulate)
    hipMemsetAsync(Wf, 0, (size_t)N_DIM * K_DIM * sizeof(float), stream);
    scatter_kernel<<<(NNZ + 255) / 256, 256, 0, stream>>>(indices, values, Wf);

    if (ws_size >= WS_NEED) {
        unsigned short* Wb = (unsigned short*)((char*)d_ws + WBF16_OFF);
        unsigned short* xb = (unsigned short*)((char*)d_ws + XB_OFF);

        // 2. fp32 -> bf16 conversions
        {
            int n4 = (N_DIM * K_DIM) / 4;
            f32_to_bf16_kernel<<<(n4 + 255) / 256, 256, 0, stream>>>(Wf, Wb, n4);
        }
        {
            int n4 = (M_DIM * K_DIM) / 4;
            f32_to_bf16_kernel<<<(n4 + 255) / 256, 256, 0, stream>>>(x, xb, n4);
        }

        // 3. 256^2 BK=64 two-barrier bf16 MFMA GEMM + ReLU
        gemm256_v4<<<(M_DIM / 256) * (N_DIM / 256), 512, 0, stream>>>(
            (const __hip_bfloat16*)xb, (const __hip_bfloat16*)Wb, out);
    } else {
        gemm_f32_fallback<<<dim3(N_DIM / 64, M_DIM / 64), 256, 0, stream>>>(
            x, Wf, out);
    }
}

// Round 5
// 362.268 us; speedup vs baseline: 7.6068x; 1.2903x over previous
//
#include <hip/hip_runtime.h>
#include <hip/hip_bf16.h>
#include <stdint.h>

#define M_DIM 8192
#define N_DIM 4096
#define K_DIM 4096
#define NNZ   1600000

typedef __attribute__((ext_vector_type(8))) short bf16x8;
typedef __attribute__((ext_vector_type(4))) float f32x4;

// workspace layout (bytes)
static const size_t WF32_OFF  = 0;
static const size_t WBF16_OFF = 64ull << 20;
static const size_t XB_OFF    = 96ull << 20;
static const size_t WS_NEED   = 160ull << 20;

__device__ __forceinline__ unsigned short f2bf(float f) {
    union { float f; uint32_t u; } a; a.f = f;
    uint32_t u = a.u;
    uint32_t r = (u + 0x7FFFu + ((u >> 16) & 1u)) >> 16;   // RNE
    return (unsigned short)r;
}

__global__ void scatter_kernel(const int* __restrict__ idx,
                               const float* __restrict__ vals,
                               float* __restrict__ W) {
    int t = blockIdx.x * blockDim.x + threadIdx.x;
    if (t < NNZ) {
        int2 rc = ((const int2*)idx)[t];
        atomicAdd(&W[(size_t)rc.x * K_DIM + rc.y], vals[t]);
    }
}

__global__ void f32_to_bf16_kernel(const float* __restrict__ src,
                                   unsigned short* __restrict__ dst, int n4) {
    int t = blockIdx.x * blockDim.x + threadIdx.x;
    if (t < n4) {
        float4 v = ((const float4*)src)[t];
        ushort4 o;
        o.x = f2bf(v.x); o.y = f2bf(v.y); o.z = f2bf(v.z); o.w = f2bf(v.w);
        ((ushort4*)dst)[t] = o;
    }
}

// ---------------------------------------------------------------------------
// 256x256 bf16 MFMA GEMM, BK=64, 8 waves (2Mx4N), per-wave 128x64 out.
// 4 compute phases per K-tile (one C-quadrant each, 16 MFMA), ONE barrier per
// phase + one boundary barrier. NO manual lgkmcnt / sched_barrier anywhere in
// the loop (m141 lesson: let the compiler emit fine-grained lgkmcnt and
// interleave ds_read issue with MFMA). Counted vmcnt(6) at the K-tile
// boundary only (3 half-tiles in flight; never 0 until the tail).
// Stage placement (after MFMA cluster of the noted phase) is write-after-read
// safe: the target region's last readers drained their reads before passing
// the barrier that precedes the staging wave's issue point.
//   ph0: read aLo(8)+bLo(4) | BAR | MFMA Q00 | stage B(t+1)h1 -> c^1
//   ph1: read aHi(8)        | BAR | MFMA Q10 |
//   ph2: read bHi(4)        | BAR | MFMA Q11 | stage A(t+2)h0,h1 -> c
//   ph3:                      BAR | MFMA Q01 | stage B(t+2)h0 -> c
//   boundary: vmcnt(6) ; BAR      (t==NT-2: vmcnt(0); t==NT-1: nothing)
// Swizzle (0-conflict, verified r1/r2): 16B slot u of row r stored at
// u^(r&7); inverse-swizzled global source keeps gload_lds dest linear.
// ---------------------------------------------------------------------------
#define GLOAD16(gp, lp) __builtin_amdgcn_global_load_lds( \
    (const __attribute__((address_space(1))) void*)(gp),  \
    (__attribute__((address_space(3))) void*)(lp), 16, 0, 0)
#define VMCNT(n)   asm volatile("s_waitcnt vmcnt(" #n ")" ::: "memory")
#define BAR()    __builtin_amdgcn_s_barrier()

// frag read from 256x64 swizzled tile: row r, k-slot kk in {0,1}
#define FRAG(T, r, kk) \
    (*(const bf16x8*)&(T)[(r) * 64 + (((((kk) << 2) + l4) ^ ((r) & 7)) << 3)])

// stage one 64-row group g (0..3) of a 256x64 tile: 1 gload x 512 thr x 16B
#define STAGE_AG(buf, tt, g) \
    GLOAD16(Ab + (size_t)((g) * 64 + rbase) * K_DIM + (size_t)(tt) * 64 + cs, \
            &sA[buf][(g) * 4096 + wid * 512])
#define STAGE_BG(buf, tt, g) \
    GLOAD16(Bb + (size_t)((g) * 64 + rbase) * K_DIM + (size_t)(tt) * 64 + cs, \
            &sB[buf][(g) * 4096 + wid * 512])

__global__ __launch_bounds__(512, 2) void gemm256_v5(
        const __hip_bfloat16* __restrict__ A,   // M x K
        const __hip_bfloat16* __restrict__ B,   // N x K
        float* __restrict__ C)                  // M x N
{
    __shared__ __align__(16) __hip_bfloat16 sA[2][256 * 64];
    __shared__ __align__(16) __hip_bfloat16 sB[2][256 * 64];

    const int tid  = threadIdx.x;
    const int lane = tid & 63;
    const int wid  = tid >> 6;
    const int wr   = wid >> 2;      // 0..1  (128-row half of A-tile)
    const int wc   = wid & 3;       // 0..3  (64-col slice of B-tile)
    const int l15  = lane & 15, l4 = lane >> 4;

    // XCD-aware bijective swizzle (nwg = 512, %8 == 0)
    const int bid = blockIdx.x;
    const int swz = (bid & 7) * 64 + (bid >> 3);
    const int m0  = (swz >> 4) * 256;   // 32 m-tiles
    const int n0  = (swz & 15) * 256;   // 16 n-tiles

    // staging geometry: slot s = tid; row-in-group = tid>>3; 16B col-slot
    // u = tid&7; inverse-swizzled source col = (u ^ (row&7))*8
    const int rbase = tid >> 3;
    const int cs    = ((tid & 7) ^ (rbase & 7)) << 3;

    const __hip_bfloat16* Ab = A + (size_t)m0 * K_DIM;
    const __hip_bfloat16* Bb = B + (size_t)n0 * K_DIM;

    f32x4 acc[8][4] = {};

    // ---- prologue: tile0 (8 loads), then A(1) full + B(1)h0 (6 loads) ----
    STAGE_AG(0, 0, 0); STAGE_AG(0, 0, 1); STAGE_AG(0, 0, 2); STAGE_AG(0, 0, 3);
    STAGE_BG(0, 0, 0); STAGE_BG(0, 0, 1); STAGE_BG(0, 0, 2); STAGE_BG(0, 0, 3);
    STAGE_AG(1, 1, 0); STAGE_AG(1, 1, 1); STAGE_AG(1, 1, 2); STAGE_AG(1, 1, 3);
    STAGE_BG(1, 1, 0); STAGE_BG(1, 1, 1);
    VMCNT(6);          // tile 0 landed; {A(1) x4, B(1)h0 x2} in flight
    BAR();

    const int NT = K_DIM / 64;      // 64
    #pragma unroll 2
    for (int t = 0; t < NT; ++t) {
        const int c = t & 1;
        const __hip_bfloat16* TA = sA[c];
        const __hip_bfloat16* TB = sB[c];

        bf16x8 aLo[4][2], aHi[4][2], bLo[2][2], bHi[2][2];

        // ---------- phase 0: Q00 = (mLo x nLo) ----------
        #pragma unroll
        for (int m = 0; m < 4; ++m) {
            const int r = wr * 128 + m * 16 + l15;
            aLo[m][0] = FRAG(TA, r, 0);
            aLo[m][1] = FRAG(TA, r, 1);
        }
        #pragma unroll
        for (int n = 0; n < 2; ++n) {
            const int r = wc * 64 + n * 16 + l15;
            bLo[n][0] = FRAG(TB, r, 0);
            bLo[n][1] = FRAG(TB, r, 1);
        }
        BAR();
        __builtin_amdgcn_s_setprio(1);
        #pragma unroll
        for (int k = 0; k < 2; ++k)
            #pragma unroll
            for (int m = 0; m < 4; ++m)
                #pragma unroll
                for (int n = 0; n < 2; ++n)
                    acc[m][n] = __builtin_amdgcn_mfma_f32_16x16x32_bf16(
                                    aLo[m][k], bLo[n][k], acc[m][n], 0, 0, 0);
        __builtin_amdgcn_s_setprio(0);
        if (t + 1 < NT) { STAGE_BG(c ^ 1, t + 1, 2); STAGE_BG(c ^ 1, t + 1, 3); }

        // ---------- phase 1: Q10 = (mHi x nLo) ----------
        #pragma unroll
        for (int m = 0; m < 4; ++m) {
            const int r = wr * 128 + 64 + m * 16 + l15;
            aHi[m][0] = FRAG(TA, r, 0);
            aHi[m][1] = FRAG(TA, r, 1);
        }
        BAR();
        __builtin_amdgcn_s_setprio(1);
        #pragma unroll
        for (int k = 0; k < 2; ++k)
            #pragma unroll
            for (int m = 0; m < 4; ++m)
                #pragma unroll
                for (int n = 0; n < 2; ++n)
                    acc[4 + m][n] = __builtin_amdgcn_mfma_f32_16x16x32_bf16(
                                    aHi[m][k], bLo[n][k], acc[4 + m][n], 0, 0, 0);
        __builtin_amdgcn_s_setprio(0);

        // ---------- phase 2: Q11 = (mHi x nHi) ----------
        #pragma unroll
        for (int n = 0; n < 2; ++n) {
            const int r = wc * 64 + 32 + n * 16 + l15;
            bHi[n][0] = FRAG(TB, r, 0);
            bHi[n][1] = FRAG(TB, r, 1);
        }
        BAR();
        __builtin_amdgcn_s_setprio(1);
        #pragma unroll
        for (int k = 0; k < 2; ++k)
            #pragma unroll
            for (int m = 0; m < 4; ++m)
                #pragma unroll
                for (int n = 0; n < 2; ++n)
                    acc[4 + m][2 + n] = __builtin_amdgcn_mfma_f32_16x16x32_bf16(
                                    aHi[m][k], bHi[n][k], acc[4 + m][2 + n], 0, 0, 0);
        __builtin_amdgcn_s_setprio(0);
        if (t + 2 < NT) {
            STAGE_AG(c, t + 2, 0); STAGE_AG(c, t + 2, 1);
            STAGE_AG(c, t + 2, 2); STAGE_AG(c, t + 2, 3);
        }

        // ---------- phase 3: Q01 = (mLo x nHi) ----------
        BAR();
        __builtin_amdgcn_s_setprio(1);
        #pragma unroll
        for (int k = 0; k < 2; ++k)
            #pragma unroll
            for (int m = 0; m < 4; ++m)
                #pragma unroll
                for (int n = 0; n < 2; ++n)
                    acc[m][2 + n] = __builtin_amdgcn_mfma_f32_16x16x32_bf16(
                                    aLo[m][k], bHi[n][k], acc[m][2 + n], 0, 0, 0);
        __builtin_amdgcn_s_setprio(0);
        if (t + 2 < NT) { STAGE_BG(c, t + 2, 0); STAGE_BG(c, t + 2, 1); }

        // ---------- K-tile boundary ----------
        if (t < NT - 2) {
            VMCNT(6);       // drains tile t+1 fully; 3 half-tiles stay in flight
            BAR();
        } else if (t == NT - 2) {
            VMCNT(0);       // tail: drain B(NT-1)h1
            BAR();
        }
        // t == NT-1: no further LDS use; fall through to epilogue
    }

    // ---- epilogue: ReLU + fp32 store ----
    const int row_base = m0 + wr * 128;
    const int col_base = n0 + wc * 64;
    #pragma unroll
    for (int m = 0; m < 8; ++m)
        #pragma unroll
        for (int n = 0; n < 4; ++n) {
            const f32x4 v = acc[m][n];
            const int col = col_base + n * 16 + l15;
            #pragma unroll
            for (int j = 0; j < 4; ++j) {
                const int row = row_base + m * 16 + l4 * 4 + j;
                C[(size_t)row * N_DIM + col] = fmaxf(v[j], 0.0f);
            }
        }
}

// ---------------------------------------------------------------------------
// fp32 fallback GEMM (only if ws_size < 160MB)
// ---------------------------------------------------------------------------
__global__ void gemm_f32_fallback(const float* __restrict__ A,
                                  const float* __restrict__ W,
                                  float* __restrict__ C) {
    __shared__ float As[64][17];
    __shared__ float Bs[64][17];
    const int tx = threadIdx.x & 15, ty = threadIdx.x >> 4;
    const int m0 = blockIdx.y * 64, n0 = blockIdx.x * 64;
    float acc[4][4] = {};
    for (int kt = 0; kt < K_DIM; kt += 16) {
        #pragma unroll
        for (int i = 0; i < 4; ++i) {
            int e = threadIdx.x + i * 256;
            int r = e >> 4, k = e & 15;
            As[r][k] = A[(size_t)(m0 + r) * K_DIM + kt + k];
            Bs[r][k] = W[(size_t)(n0 + r) * K_DIM + kt + k];
        }
        __syncthreads();
        #pragma unroll
        for (int k = 0; k < 16; ++k) {
            float av[4], bv[4];
            #pragma unroll
            for (int i = 0; i < 4; ++i) av[i] = As[ty * 4 + i][k];
            #pragma unroll
            for (int i = 0; i < 4; ++i) bv[i] = Bs[tx * 4 + i][k];
            #pragma unroll
            for (int i = 0; i < 4; ++i)
                #pragma unroll
                for (int j = 0; j < 4; ++j) acc[i][j] += av[i] * bv[j];
        }
        __syncthreads();
    }
    #pragma unroll
    for (int i = 0; i < 4; ++i)
        #pragma unroll
        for (int j = 0; j < 4; ++j)
            C[(size_t)(m0 + ty * 4 + i) * N_DIM + n0 + tx * 4 + j] =
                fmaxf(acc[i][j], 0.0f);
}

extern "C" void kernel_launch(void* const* d_in, const int* in_sizes, int n_in,
                              void* d_out, int out_size, void* d_ws, size_t ws_size,
                              hipStream_t stream) {
    const float* x       = (const float*)d_in[0];
    const int*   indices = (const int*)d_in[1];
    const float* values  = (const float*)d_in[2];
    float*       out     = (float*)d_out;

    float* Wf = (float*)((char*)d_ws + WF32_OFF);

    // 1. zero + scatter-build W (fp32, duplicates accumulate)
    hipMemsetAsync(Wf, 0, (size_t)N_DIM * K_DIM * sizeof(float), stream);
    scatter_kernel<<<(NNZ + 255) / 256, 256, 0, stream>>>(indices, values, Wf);

    if (ws_size >= WS_NEED) {
        unsigned short* Wb = (unsigned short*)((char*)d_ws + WBF16_OFF);
        unsigned short* xb = (unsigned short*)((char*)d_ws + XB_OFF);

        // 2. fp32 -> bf16 conversions
        {
            int n4 = (N_DIM * K_DIM) / 4;
            f32_to_bf16_kernel<<<(n4 + 255) / 256, 256, 0, stream>>>(Wf, Wb, n4);
        }
        {
            int n4 = (M_DIM * K_DIM) / 4;
            f32_to_bf16_kernel<<<(n4 + 255) / 256, 256, 0, stream>>>(x, xb, n4);
        }

        // 3. 256^2 4-phase (compiler-scheduled waits) bf16 MFMA GEMM + ReLU
        gemm256_v5<<<(M_DIM / 256) * (N_DIM / 256), 512, 0, stream>>>(
            (const __hip_bfloat16*)xb, (const __hip_bfloat16*)Wb, out);
    } else {
        gemm_f32_fallback<<<dim3(N_DIM / 64, M_DIM / 64), 256, 0, stream>>>(
            x, Wf, out);
    }
}